// Round 1
// baseline (2717.874 us; speedup 1.0000x reference)
//
#include <hip/hip_runtime.h>
#include <hip/hip_bf16.h>

#define BB 256
#define TT 128
#define NN 1024
#define HH 1024
#define G4 4096

typedef __attribute__((ext_vector_type(4))) float f32x4;
typedef __attribute__((ext_vector_type(8))) short bf16x8;

__device__ __forceinline__ unsigned short f2bf(float f) {
    unsigned int u = __builtin_bit_cast(unsigned int, f);
    u += 0x7FFFu + ((u >> 16) & 1u);
    return (unsigned short)(u >> 16);
}
__device__ __forceinline__ float bf2f(unsigned short s) {
    unsigned int u = ((unsigned int)s) << 16;
    return __builtin_bit_cast(float, u);
}

// ---------------------------------------------------------------------------
// K1: attention weights (time-invariant!) + input_weighted (f32) + w_in bf16
// grid = B blocks, 512 threads (each owns 2 consecutive n)
// ---------------------------------------------------------------------------
__global__ __launch_bounds__(512) void k_attn(
    const float* __restrict__ x, const float* __restrict__ attn_w,
    const float* __restrict__ attn_b, float* __restrict__ out0,
    unsigned short* __restrict__ win_bf)
{
    const int b = blockIdx.x;
    const int tid = threadIdx.x;            // 0..511
    const float* xb = x + (size_t)b * (TT * NN);
    const float* wx = attn_w + 2 * HH;

    float s0 = 0.f, s1 = 0.f;
    for (int t = 0; t < TT; ++t) {
        float2 v = *(const float2*)(xb + (size_t)t * NN + tid * 2);
        float w = wx[t];
        s0 += v.x * w; s1 += v.y * w;
    }
    float ab = attn_b[0];
    s0 += ab; s1 += ab;

    // softmax over the 1024 values (2 per thread)
    __shared__ float red[8];
    const int wv = tid >> 6, ln = tid & 63;
    float m = fmaxf(s0, s1);
#pragma unroll
    for (int off = 32; off > 0; off >>= 1) m = fmaxf(m, __shfl_xor(m, off));
    if (ln == 0) red[wv] = m;
    __syncthreads();
    m = red[0];
#pragma unroll
    for (int i = 1; i < 8; ++i) m = fmaxf(m, red[i]);

    float e0 = expf(s0 - m), e1 = expf(s1 - m);
    float sum = e0 + e1;
#pragma unroll
    for (int off = 32; off > 0; off >>= 1) sum += __shfl_xor(sum, off);
    __syncthreads();                         // red reuse
    if (ln == 0) red[wv] = sum;
    __syncthreads();
    sum = 0.f;
#pragma unroll
    for (int i = 0; i < 8; ++i) sum += red[i];
    const float inv = 1.0f / sum;
    const float a0 = e0 * inv, a1 = e1 * inv;

    float* o = out0 + (size_t)b * (TT * NN);
    unsigned short* wb = win_bf + (size_t)b * (TT * NN);
    for (int t = 0; t < TT; ++t) {
        float2 v = *(const float2*)(xb + (size_t)t * NN + tid * 2);
        float2 w; w.x = a0 * v.x; w.y = a1 * v.y;
        *(float2*)(o + (size_t)t * NN + tid * 2) = w;
        unsigned int pk = (unsigned int)f2bf(w.x) | ((unsigned int)f2bf(w.y) << 16);
        *(unsigned int*)(wb + (size_t)t * NN + tid * 2) = pk;
    }
}

// ---------------------------------------------------------------------------
// K2: convert W_ih / W_hh to bf16 with gate-interleaved row permutation
//     perm row p = j*4 + g  <-  source row r = g*1024 + j.  Also bias sum.
// grid = 4096 blocks (one per perm row), 256 threads
// ---------------------------------------------------------------------------
__global__ __launch_bounds__(256) void k_prep_w(
    const float* __restrict__ Wih, const float* __restrict__ Whh,
    const float* __restrict__ bih, const float* __restrict__ bhh,
    unsigned short* __restrict__ WihP, unsigned short* __restrict__ WhhP,
    float* __restrict__ biasP)
{
    const int p = blockIdx.x;
    const int j = p >> 2, g = p & 3;
    const int r = g * HH + j;
    const int tid = threadIdx.x;
    {
        float4 v = *(const float4*)(Wih + (size_t)r * NN + tid * 4);
        ushort4 o;
        o.x = f2bf(v.x); o.y = f2bf(v.y); o.z = f2bf(v.z); o.w = f2bf(v.w);
        *(ushort4*)(WihP + (size_t)p * NN + tid * 4) = o;
    }
    {
        float4 v = *(const float4*)(Whh + (size_t)r * HH + tid * 4);
        ushort4 o;
        o.x = f2bf(v.x); o.y = f2bf(v.y); o.z = f2bf(v.z); o.w = f2bf(v.w);
        *(ushort4*)(WhhP + (size_t)p * HH + tid * 4) = o;
    }
    if (tid == 0) biasP[p] = bih[r] + bhh[r];
}

// ---------------------------------------------------------------------------
// K3: Xp = w_in_bf16 (32768,1024) @ WihP^T (4096,1024) -> bf16 (32768,4096)
//     m97 recipe: 128x128 tile, BK=32, 4 waves (64x64 each), 16x16x32 MFMA,
//     global_load_lds width 16, 2-barrier K-loop, XCD swizzle.
// grid = 256*32 = 8192 blocks, 256 threads
// ---------------------------------------------------------------------------
__global__ __launch_bounds__(256) void k_gemm_xp(
    const unsigned short* __restrict__ A,
    const unsigned short* __restrict__ Bm,
    unsigned short* __restrict__ C)
{
    __shared__ unsigned short lA[128 * 32];
    __shared__ unsigned short lB[128 * 32];

    const int bid = blockIdx.x;
    const int cpx = gridDim.x >> 3;                 // 8192 % 8 == 0 -> bijective
    const int swz = (bid & 7) * cpx + (bid >> 3);
    const int NTN = G4 / 128;                       // 32
    const int tm = swz / NTN, tn = swz % NTN;

    const int tid = threadIdx.x;
    const int wv = tid >> 6, ln = tid & 63;
    const int wr = wv >> 1, wc = wv & 1;

    f32x4 acc[4][4] = {};

    const unsigned short* Ag = A + (size_t)tm * 128 * NN;
    const unsigned short* Bg = Bm + (size_t)tn * 128 * NN;
    const int srow = ln >> 2;                       // 0..15
    const int sseg = ln & 3;

    for (int k0 = 0; k0 < NN; k0 += 32) {
        __syncthreads();
#pragma unroll
        for (int q = 0; q < 2; ++q) {
            const int row = wv * 32 + q * 16 + srow;
            __builtin_amdgcn_global_load_lds(
                (const __attribute__((address_space(1))) void*)(Ag + (size_t)row * NN + k0 + sseg * 8),
                (__attribute__((address_space(3))) void*)(&lA[(wv * 32 + q * 16) * 32]),
                16, 0, 0);
            __builtin_amdgcn_global_load_lds(
                (const __attribute__((address_space(1))) void*)(Bg + (size_t)row * NN + k0 + sseg * 8),
                (__attribute__((address_space(3))) void*)(&lB[(wv * 32 + q * 16) * 32]),
                16, 0, 0);
        }
        __syncthreads();

        const int rlo = ln & 15, khi = ln >> 4;
        bf16x8 af[4], bfr[4];
#pragma unroll
        for (int m = 0; m < 4; ++m)
            af[m] = *(const bf16x8*)&lA[(wr * 64 + m * 16 + rlo) * 32 + khi * 8];
#pragma unroll
        for (int n = 0; n < 4; ++n)
            bfr[n] = *(const bf16x8*)&lB[(wc * 64 + n * 16 + rlo) * 32 + khi * 8];
#pragma unroll
        for (int m = 0; m < 4; ++m)
#pragma unroll
            for (int n = 0; n < 4; ++n)
                acc[m][n] = __builtin_amdgcn_mfma_f32_16x16x32_bf16(af[m], bfr[n], acc[m][n], 0, 0, 0);
    }

    const int rlo = ln & 15, rhi = ln >> 4;
#pragma unroll
    for (int m = 0; m < 4; ++m)
#pragma unroll
        for (int n = 0; n < 4; ++n)
#pragma unroll
            for (int j = 0; j < 4; ++j) {
                const int row = tm * 128 + wr * 64 + m * 16 + rhi * 4 + j;
                const int col = tn * 128 + wc * 64 + n * 16 + rlo;
                C[(size_t)row * G4 + col] = f2bf(acc[m][n][j]);
            }
}

// ---------------------------------------------------------------------------
// K4 (per step t): G' = h_bf @ WhhP^T (perm cols), + Xp + bias, LSTM update.
//     Block = 64 batch x 64 perm-cols (= 16 hidden units x 4 gates).
// grid = 4*64 = 256 blocks, 256 threads (4 waves, 32x32 wave tiles)
// ---------------------------------------------------------------------------
__global__ __launch_bounds__(256) void k_step(
    const int t,
    const unsigned short* __restrict__ hbf,
    const unsigned short* __restrict__ WhhP,
    const unsigned short* __restrict__ Xp,
    const float* __restrict__ biasP,
    float* __restrict__ cbuf,
    unsigned short* __restrict__ hbf_out,
    float* __restrict__ out1)
{
    __shared__ unsigned short lA[64 * 32];
    __shared__ unsigned short lB[64 * 32];
    __shared__ float gsm[64][65];

    const int bid = blockIdx.x;
    const int ti = bid >> 6;                        // batch tile 0..3
    const int tj = bid & 63;                        // col tile 0..63
    const int tid = threadIdx.x;
    const int wv = tid >> 6, ln = tid & 63;
    const int wr = wv >> 1, wc = wv & 1;

    f32x4 acc[2][2] = {};

    const unsigned short* Ag = hbf + (size_t)ti * 64 * HH;
    const unsigned short* Bg = WhhP + (size_t)tj * 64 * HH;
    const int srow = ln >> 2, sseg = ln & 3;

    for (int k0 = 0; k0 < HH; k0 += 32) {
        __syncthreads();
        {
            const int row = wv * 16 + srow;
            __builtin_amdgcn_global_load_lds(
                (const __attribute__((address_space(1))) void*)(Ag + (size_t)row * HH + k0 + sseg * 8),
                (__attribute__((address_space(3))) void*)(&lA[(wv * 16) * 32]),
                16, 0, 0);
            __builtin_amdgcn_global_load_lds(
                (const __attribute__((address_space(1))) void*)(Bg + (size_t)row * HH + k0 + sseg * 8),
                (__attribute__((address_space(3))) void*)(&lB[(wv * 16) * 32]),
                16, 0, 0);
        }
        __syncthreads();

        const int rlo = ln & 15, khi = ln >> 4;
        bf16x8 af[2], bfr[2];
#pragma unroll
        for (int m = 0; m < 2; ++m)
            af[m] = *(const bf16x8*)&lA[(wr * 32 + m * 16 + rlo) * 32 + khi * 8];
#pragma unroll
        for (int n = 0; n < 2; ++n)
            bfr[n] = *(const bf16x8*)&lB[(wc * 32 + n * 16 + rlo) * 32 + khi * 8];
#pragma unroll
        for (int m = 0; m < 2; ++m)
#pragma unroll
            for (int n = 0; n < 2; ++n)
                acc[m][n] = __builtin_amdgcn_mfma_f32_16x16x32_bf16(af[m], bfr[n], acc[m][n], 0, 0, 0);
    }

    {
        const int rlo = ln & 15, rhi = ln >> 4;
#pragma unroll
        for (int m = 0; m < 2; ++m)
#pragma unroll
            for (int n = 0; n < 2; ++n)
#pragma unroll
                for (int j = 0; j < 4; ++j)
                    gsm[wr * 32 + m * 16 + rhi * 4 + j][wc * 32 + n * 16 + rlo] = acc[m][n][j];
    }
    __syncthreads();

    // fused LSTM pointwise update; thread -> (jl, bq), 4 batch rows each
    const int jl = tid & 15;
    const int bq = tid >> 4;
    const float4 bias4 = *(const float4*)&biasP[tj * 64 + jl * 4];
#pragma unroll
    for (int q = 0; q < 4; ++q) {
        const int bl = q * 16 + bq;
        const int bg = ti * 64 + bl;
        const int jg = tj * 16 + jl;
        ushort4 xp4 = *(const ushort4*)&Xp[((size_t)bg * TT + t) * G4 + tj * 64 + jl * 4];
        float gi = gsm[bl][jl * 4 + 0] + bf2f(xp4.x) + bias4.x;
        float gf = gsm[bl][jl * 4 + 1] + bf2f(xp4.y) + bias4.y;
        float gg = gsm[bl][jl * 4 + 2] + bf2f(xp4.z) + bias4.z;
        float go = gsm[bl][jl * 4 + 3] + bf2f(xp4.w) + bias4.w;
        float i_ = 1.f / (1.f + expf(-gi));
        float f_ = 1.f / (1.f + expf(-gf));
        float g_ = tanhf(gg);
        float o_ = 1.f / (1.f + expf(-go));
        float c_ = f_ * cbuf[(size_t)bg * HH + jg] + i_ * g_;
        cbuf[(size_t)bg * HH + jg] = c_;
        float h_ = o_ * tanhf(c_);
        out1[(size_t)bg * (TT * HH) + (size_t)t * HH + jg] = h_;
        hbf_out[(size_t)bg * HH + jg] = f2bf(h_);
    }
}

// zero-init kernel (avoid memset-in-capture doubts): clears 2 MiB region
__global__ __launch_bounds__(256) void k_zero(float4* __restrict__ p)
{
    p[blockIdx.x * 256 + threadIdx.x] = make_float4(0.f, 0.f, 0.f, 0.f);
}

extern "C" void kernel_launch(void* const* d_in, const int* in_sizes, int n_in,
                              void* d_out, int out_size, void* d_ws, size_t ws_size,
                              hipStream_t stream)
{
    const float* x      = (const float*)d_in[0];
    const float* Wih    = (const float*)d_in[1];
    const float* Whh    = (const float*)d_in[2];
    const float* bih    = (const float*)d_in[3];
    const float* bhh    = (const float*)d_in[4];
    const float* attn_w = (const float*)d_in[5];
    const float* attn_b = (const float*)d_in[6];

    float* out0 = (float*)d_out;                               // (B,T,N)
    float* out1 = (float*)d_out + (size_t)BB * TT * NN;        // (B,T,H)

    char* w = (char*)d_ws;
    unsigned short* WihP  = (unsigned short*)(w);                       //  8 MiB
    unsigned short* WhhP  = (unsigned short*)(w + 8388608);             //  8 MiB
    float*          biasP = (float*)(w + 16777216);                     // 16 KiB
    unsigned short* winbf = (unsigned short*)(w + 16793600);            // 64 MiB
    unsigned short* Xp    = (unsigned short*)(w + 83902464);            // 256 MiB
    unsigned short* hbf0  = (unsigned short*)(w + 352337920);           // 512 KiB
    unsigned short* hbf1  = (unsigned short*)(w + 352862208);           // 512 KiB
    float*          cbuf  = (float*)(w + 353386496);                    //   1 MiB
    // total 354,435,072 bytes

    k_attn<<<BB, 512, 0, stream>>>(x, attn_w, attn_b, out0, winbf);
    k_prep_w<<<G4, 256, 0, stream>>>(Wih, Whh, bih, bhh, WihP, WhhP, biasP);
    k_gemm_xp<<<(BB * TT / 128) * (G4 / 128), 256, 0, stream>>>(winbf, WihP, Xp);
    // zero h(t=0) and c: hbf0|hbf1|cbuf are contiguous 2 MiB
    k_zero<<<512, 256, 0, stream>>>((float4*)hbf0);

    for (int t = 0; t < TT; ++t) {
        const unsigned short* hin = (t & 1) ? hbf1 : hbf0;
        unsigned short* hout      = (t & 1) ? hbf0 : hbf1;
        k_step<<<256, 256, 0, stream>>>(t, hin, WhhP, Xp, biasP, cbuf, hout, out1);
    }
}